// Round 8
// baseline (940.422 us; speedup 1.0000x reference)
//
#include <hip/hip_runtime.h>

#define BLK 256

// ============================== helpers =====================================

__device__ __forceinline__ void block_stats2(float s, float q, float* partOut) {
  __shared__ float red2[2][4];
  const int lane = threadIdx.x & 63;
  const int wv   = threadIdx.x >> 6;
#pragma unroll
  for (int off = 32; off > 0; off >>= 1) {
    s += __shfl_down(s, off, 64);
    q += __shfl_down(q, off, 64);
  }
  if (lane == 0) { red2[0][wv] = s; red2[1][wv] = q; }
  __syncthreads();
  if (threadIdx.x == 0) {
    partOut[0] = red2[0][0] + red2[0][1] + red2[0][2] + red2[0][3];
    partOut[1] = red2[1][0] + red2[1][1] + red2[1][2] + red2[1][3];
  }
}

// ======================= weight transpose kernels ===========================
// target layout wt[((ci*4+kh)*4+kw)*CO + co]  (co contiguous -> s_load)

__global__ __launch_bounds__(BLK) void twc_k(const float* __restrict__ w,
                                             float* __restrict__ wt,
                                             int CI, int CO) {
  const int total = CI * CO * 16;
  for (int i = threadIdx.x; i < total; i += BLK) {
    const int co = i % CO;
    const int rest = i / CO;
    const int kw = rest & 3, kh = (rest >> 2) & 3, ci = rest >> 4;
    wt[i] = w[(co * CI + ci) * 16 + kh * 4 + kw];     // conv: w[co][ci][kh][kw]
  }
}

__global__ __launch_bounds__(BLK) void twt_k(const float* __restrict__ w,
                                             float* __restrict__ wt,
                                             int CI, int CO) {
  const int total = CI * CO * 16;
  for (int i = threadIdx.x; i < total; i += BLK) {
    const int co = i % CO;
    const int rest = i / CO;
    const int kw = rest & 3, kh = (rest >> 2) & 3, ci = rest >> 4;
    wt[i] = w[(ci * CO + co) * 16 + kh * 4 + kw];     // convT: w[ci][co][kh][kw]
  }
}

// ============ conv (k4 s2 p1), wave-cg split, scalar-mem weights ============
// Block: PW position-waves x CGN co-group-waves (cg wave-uniform -> s_load).
// FMA chain per co is IDENTICAL to round-7 conv_s (kh->kw->ci, same skips);
// per-block BN partials cover the same 64*PW positions with the same 4-wave
// tree order -> encoder output bit-identical.

template<int CI, int CO, int CGN, int PW, int HIN, int WIN, bool BN_IN>
__global__ __launch_bounds__(64 * PW * CGN) void conv_cg(
    const float* __restrict__ in, const float* __restrict__ wt,
    const float* __restrict__ bias,
    const float* __restrict__ scIn, const float* __restrict__ shIn,
    float* __restrict__ out, float* __restrict__ part)
{
  constexpr int HOUT = HIN / 2, WOUT = WIN / 2;
  constexpr int COG = CO / CGN;
  const int lane = threadIdx.x & 63;
  const int w    = threadIdx.x >> 6;
  const int pw   = w & (PW - 1);
  const int cg   = w / PW;
  const int co0  = cg * COG;

  float sc[CI], sh[CI];
  if constexpr (BN_IN) {
#pragma unroll
    for (int ci = 0; ci < CI; ++ci) { sc[ci] = scIn[ci]; sh[ci] = shIn[ci]; }
  }

  const int pos = blockIdx.x * (64 * PW) + pw * 64 + lane;
  const int ow  = pos % WOUT;
  const int oh  = (pos / WOUT) % HOUT;
  const int b   = pos / (WOUT * HOUT);

  float acc[COG];
#pragma unroll
  for (int j = 0; j < COG; ++j) acc[j] = bias[co0 + j];

  const float* inb = in + (size_t)b * CI * HIN * WIN;

#pragma unroll
  for (int kh = 0; kh < 4; ++kh) {
    const int ih = oh * 2 - 1 + kh;
    if ((unsigned)ih < (unsigned)HIN) {
#pragma unroll
      for (int kw = 0; kw < 4; ++kw) {
        const int iw = ow * 2 - 1 + kw;
        if ((unsigned)iw < (unsigned)WIN) {
#pragma unroll 2
          for (int ci = 0; ci < CI; ++ci) {
            float v = inb[(ci * HIN + ih) * WIN + iw];
            if constexpr (BN_IN) v = fmaxf(fmaf(sc[ci], v, sh[ci]), 0.f);
            const float* wrow = wt + ((ci * 4 + kh) * 4 + kw) * CO + co0; // uniform
#pragma unroll
            for (int j = 0; j < COG; ++j)
              acc[j] = fmaf(v, wrow[j], acc[j]);
          }
        }
      }
    }
  }

#pragma unroll
  for (int j = 0; j < COG; ++j)
    out[((size_t)(b * CO + co0 + j) * HOUT + oh) * WOUT + ow] = acc[j];

  // BN partials: per-wave 64-lane tree, then sum PW pos-waves in order.
  float s[COG], q[COG];
#pragma unroll
  for (int j = 0; j < COG; ++j) { s[j] = acc[j]; q[j] = acc[j] * acc[j]; }
#pragma unroll
  for (int off = 32; off > 0; off >>= 1)
#pragma unroll
    for (int j = 0; j < COG; ++j) {
      s[j] += __shfl_down(s[j], off, 64);
      q[j] += __shfl_down(q[j], off, 64);
    }
  __shared__ float red[CGN * PW][COG][2];
  if (lane == 0) {
#pragma unroll
    for (int j = 0; j < COG; ++j) { red[w][j][0] = s[j]; red[w][j][1] = q[j]; }
  }
  __syncthreads();
  if (threadIdx.x < CO) {
    const int co = threadIdx.x;
    const int cg2 = co / COG, j = co % COG;
    float ss = 0.f, qq = 0.f;
#pragma unroll
    for (int p2 = 0; p2 < PW; ++p2) {
      ss += red[cg2 * PW + p2][j][0];
      qq += red[cg2 * PW + p2][j][1];
    }
    part[(size_t)blockIdx.x * CO * 2 + co * 2]     = ss;
    part[(size_t)blockIdx.x * CO * 2 + co * 2 + 1] = qq;
  }
}

// ===== transposed conv parity-quad, wave-cg split (CO=16, uniform s_load) ===
// Thread computes the 2x2 quad for COG co's; cg is wave-uniform.

template<int CI, int CGN, int PW, int HIN, bool BN_IN>
__global__ __launch_bounds__(64 * PW * CGN) void convTq_cg(
    const float* __restrict__ in, const float* __restrict__ wt,
    const float* __restrict__ bias,
    const float* __restrict__ scIn, const float* __restrict__ shIn,
    float* __restrict__ out, float* __restrict__ part)
{
  constexpr int WIN = HIN, HOUT = 2 * HIN, WOUT = 2 * WIN;
  constexpr int COG = 16 / CGN;
  const int lane = threadIdx.x & 63;
  const int w    = threadIdx.x >> 6;
  const int pw   = w & (PW - 1);
  const int cg   = w / PW;
  const int co0  = cg * COG;

  const int q_  = blockIdx.x * (64 * PW) + pw * 64 + lane;
  const int qw  = q_ % WIN;
  const int qh  = (q_ / WIN) % HIN;
  const int b   = q_ / (WIN * HIN);

  constexpr int KH[2][2] = {{1, 3}, {0, 2}};
  constexpr int PR[2][2] = {{1, 0}, {2, 1}};

  float acc[2][2][COG];
#pragma unroll
  for (int j = 0; j < COG; ++j) {
    const float bv = bias[co0 + j];
    acc[0][0][j] = bv; acc[0][1][j] = bv;
    acc[1][0][j] = bv; acc[1][1][j] = bv;
  }

  const float* inb = in + (size_t)b * CI * HIN * WIN;

#pragma unroll 2
  for (int ci = 0; ci < CI; ++ci) {
    float sci, shi;
    if constexpr (BN_IN) { sci = scIn[ci]; shi = shIn[ci]; }
    const float* base = inb + ci * HIN * WIN;
    float v[3][3];
#pragma unroll
    for (int pr = 0; pr < 3; ++pr) {
      const int ih = qh - 1 + pr;
      const bool okr = (unsigned)ih < (unsigned)HIN;
#pragma unroll
      for (int pc = 0; pc < 3; ++pc) {
        const int iw = qw - 1 + pc;
        float val = 0.f;
        if (okr && (unsigned)iw < (unsigned)WIN) {
          val = base[ih * WIN + iw];
          if constexpr (BN_IN) val = fmaxf(fmaf(sci, val, shi), 0.f);
        }
        v[pr][pc] = val;
      }
    }
#pragma unroll
    for (int py = 0; py < 2; ++py)
#pragma unroll
      for (int tr = 0; tr < 2; ++tr) {
        const int kh = KH[py][tr], pr_ = PR[py][tr];
#pragma unroll
        for (int px = 0; px < 2; ++px)
#pragma unroll
          for (int tc = 0; tc < 2; ++tc) {
            const int kw = KH[px][tc], pc_ = PR[px][tc];
            const float* wrow = wt + ((ci * 4 + kh) * 4 + kw) * 16 + co0; // uniform
            const float pv = v[pr_][pc_];
#pragma unroll
            for (int j = 0; j < COG; ++j)
              acc[py][px][j] = fmaf(pv, wrow[j], acc[py][px][j]);
          }
      }
  }

  float* ob = out + (size_t)b * 16 * HOUT * WOUT;
#pragma unroll
  for (int j = 0; j < COG; ++j)
#pragma unroll
    for (int py = 0; py < 2; ++py) {
      float2 o; o.x = acc[py][0][j]; o.y = acc[py][1][j];
      *(float2*)&ob[((size_t)(co0 + j) * HOUT + 2 * qh + py) * WOUT + 2 * qw] = o;
    }

  float s[COG], q[COG];
#pragma unroll
  for (int j = 0; j < COG; ++j) {
    float a = acc[0][0][j] + acc[0][1][j] + acc[1][0][j] + acc[1][1][j];
    float qq = acc[0][0][j] * acc[0][0][j];
    qq = fmaf(acc[0][1][j], acc[0][1][j], qq);
    qq = fmaf(acc[1][0][j], acc[1][0][j], qq);
    qq = fmaf(acc[1][1][j], acc[1][1][j], qq);
    s[j] = a; q[j] = qq;
  }
#pragma unroll
  for (int off = 32; off > 0; off >>= 1)
#pragma unroll
    for (int j = 0; j < COG; ++j) {
      s[j] += __shfl_down(s[j], off, 64);
      q[j] += __shfl_down(q[j], off, 64);
    }
  __shared__ float red[CGN * PW][COG][2];
  if (lane == 0) {
#pragma unroll
    for (int j = 0; j < COG; ++j) { red[w][j][0] = s[j]; red[w][j][1] = q[j]; }
  }
  __syncthreads();
  if (threadIdx.x < 16) {
    const int co = threadIdx.x;
    const int cg2 = co / COG, j = co % COG;
    float ss = 0.f, qq = 0.f;
#pragma unroll
    for (int p2 = 0; p2 < PW; ++p2) {
      ss += red[cg2 * PW + p2][j][0];
      qq += red[cg2 * PW + p2][j][1];
    }
    part[(size_t)blockIdx.x * 32 + co * 2]     = ss;
    part[(size_t)blockIdx.x * 32 + co * 2 + 1] = qq;
  }
}

// ==================== convT3: 4x4-tile version (CI=16, CO=1) ================
// (unchanged — verified)

__global__ __launch_bounds__(BLK) void convT3q_k(
    const float* __restrict__ in, const float* __restrict__ w,
    const float* __restrict__ bias,
    const float* __restrict__ scIn, const float* __restrict__ shIn,
    float* __restrict__ out, float* __restrict__ part)
{
  __shared__ float wl[256];               // [ci][kh][kw]
  wl[threadIdx.x] = w[threadIdx.x];
  float sc[16], sh[16];
#pragma unroll
  for (int ci = 0; ci < 16; ++ci) { sc[ci] = scIn[ci]; sh[ci] = shIn[ci]; }
  const float b0 = bias[0];
  __syncthreads();

  const int idx = blockIdx.x * BLK + threadIdx.x;
  const int tx = idx & 63;
  const int ty = (idx >> 6) & 63;
  const int b  = idx >> 12;
  const int i0 = ty * 2, j0 = tx * 2;

  constexpr int TAP[4][4] = {{1,1,3,0},{0,2,2,1},{1,2,3,1},{0,3,2,2}};

  float acc[4][4];
#pragma unroll
  for (int r = 0; r < 4; ++r)
#pragma unroll
    for (int c = 0; c < 4; ++c) acc[r][c] = b0;

  const float* inb = in + (size_t)b * 16 * 16384;

#pragma unroll 4
  for (int ci = 0; ci < 16; ++ci) {
    const float sci = sc[ci], shi = sh[ci];
    const float* base = inb + ci * 16384;
    float v[4][4];
#pragma unroll
    for (int pr = 0; pr < 4; ++pr) {
      const int ih = i0 - 1 + pr;
      const bool okr = (unsigned)ih < 128u;
#pragma unroll
      for (int pc = 0; pc < 4; ++pc) {
        const int iw = j0 - 1 + pc;
        float val = 0.f;
        if (okr && (unsigned)iw < 128u)
          val = fmaxf(fmaf(sci, base[ih * 128 + iw], shi), 0.f);
        v[pr][pc] = val;
      }
    }
    const float4 w0 = *(const float4*)&wl[ci * 16 + 0];
    const float4 w1 = *(const float4*)&wl[ci * 16 + 4];
    const float4 w2 = *(const float4*)&wl[ci * 16 + 8];
    const float4 w3 = *(const float4*)&wl[ci * 16 + 12];
    const float wg[16] = {w0.x,w0.y,w0.z,w0.w, w1.x,w1.y,w1.z,w1.w,
                          w2.x,w2.y,w2.z,w2.w, w3.x,w3.y,w3.z,w3.w};
#pragma unroll
    for (int r = 0; r < 4; ++r) {
      const int k1r = TAP[r][0], p1r = TAP[r][1], k2r = TAP[r][2], p2r = TAP[r][3];
#pragma unroll
      for (int c = 0; c < 4; ++c) {
        const int k1c = TAP[c][0], p1c = TAP[c][1], k2c = TAP[c][2], p2c = TAP[c][3];
        float a = acc[r][c];
        a = fmaf(v[p1r][p1c], wg[k1r * 4 + k1c], a);
        a = fmaf(v[p1r][p2c], wg[k1r * 4 + k2c], a);
        a = fmaf(v[p2r][p1c], wg[k2r * 4 + k1c], a);
        a = fmaf(v[p2r][p2c], wg[k2r * 4 + k2c], a);
        acc[r][c] = a;
      }
    }
  }

  float* ob = out + (size_t)b * 65536;
#pragma unroll
  for (int r = 0; r < 4; ++r) {
    float4 o;
    o.x = acc[r][0]; o.y = acc[r][1]; o.z = acc[r][2]; o.w = acc[r][3];
    *(float4*)&ob[(ty * 4 + r) * 256 + tx * 4] = o;
  }

  float s = 0.f, q = 0.f;
#pragma unroll
  for (int r = 0; r < 4; ++r)
#pragma unroll
    for (int c = 0; c < 4; ++c) { s += acc[r][c]; q = fmaf(acc[r][c], acc[r][c], q); }
  block_stats2(s, q, part + (size_t)blockIdx.x * 2);
}

// =========================== BN stats reduction =============================

template<int C>
__global__ __launch_bounds__(BLK) void stats_k(
    const float* __restrict__ part, int nB, double N,
    const float* __restrict__ g, const float* __restrict__ be,
    float* __restrict__ sc, float* __restrict__ sh)
{
  const int c = blockIdx.x;
  double s0 = 0.0, s1 = 0.0;
  for (int i = threadIdx.x; i < nB; i += BLK) {
    s0 += (double)part[(size_t)i * C * 2 + c * 2];
    s1 += (double)part[(size_t)i * C * 2 + c * 2 + 1];
  }
  __shared__ double lds[8];
  const int lane = threadIdx.x & 63, wv = threadIdx.x >> 6;
#pragma unroll
  for (int off = 32; off > 0; off >>= 1) {
    s0 += __shfl_down(s0, off, 64);
    s1 += __shfl_down(s1, off, 64);
  }
  if (lane == 0) { lds[wv * 2] = s0; lds[wv * 2 + 1] = s1; }
  __syncthreads();
  if (threadIdx.x == 0) {
    s0 = lds[0] + lds[2] + lds[4] + lds[6];
    s1 = lds[1] + lds[3] + lds[5] + lds[7];
    const double mean = s0 / N;
    const double var  = s1 / N - mean * mean;
    const double inv  = 1.0 / sqrt(var + 1e-5);
    sc[c] = (float)((double)g[c] * inv);
    sh[c] = (float)((double)be[c] - mean * (double)g[c] * inv);
  }
}

// ============================== quantizer ===================================

__global__ __launch_bounds__(BLK) void cbn_k(const float* __restrict__ cbg,
                                             float* __restrict__ cbn)
{
  const int k = blockIdx.x * BLK + threadIdx.x;
  float s = 0.f;
#pragma unroll
  for (int c = 0; c < 32; ++c) {
    const float x = cbg[k * 32 + c];
    s = fmaf(x, x, s);
  }
  cbn[k] = s;
}

__global__ __launch_bounds__(BLK) void quantp_k(
    const float* __restrict__ y3, const float* __restrict__ cbg,
    const float* __restrict__ cbnG,
    const float* __restrict__ sc, const float* __restrict__ sh,
    float* __restrict__ bd, int* __restrict__ bki)
{
  __shared__ float cb[64 * 32];
  __shared__ float cbnl[64];
  const int pblk  = blockIdx.x & 63;
  const int chunk = blockIdx.x >> 6;
  for (int i = threadIdx.x; i < 2048; i += BLK) cb[i] = cbg[chunk * 2048 + i];
  if (threadIdx.x < 64) cbnl[threadIdx.x] = cbnG[chunk * 64 + threadIdx.x];
  __syncthreads();

  const int pos0 = pblk * 1024 + threadIdx.x;

  float z[4][32];
#pragma unroll
  for (int c = 0; c < 32; ++c) {
    const float s_ = sc[c], h_ = sh[c];
#pragma unroll
    for (int j = 0; j < 4; ++j) {
      const int pos = pos0 + j * 256;
      const int bb = pos >> 10, pp = pos & 1023;
      z[j][c] = fmaxf(fmaf(s_, y3[((size_t)(bb * 32 + c)) * 1024 + pp], h_), 0.f);
    }
  }

  float best[4] = {3.402823466e38f, 3.402823466e38f, 3.402823466e38f, 3.402823466e38f};
  int   bk[4]   = {0, 0, 0, 0};

  for (int k = 0; k < 64; ++k) {
    const float4* row = (const float4*)&cb[k * 32];
    float d[4] = {0.f, 0.f, 0.f, 0.f};
#pragma unroll
    for (int c4 = 0; c4 < 8; ++c4) {
      const float4 cc = row[c4];
#pragma unroll
      for (int j = 0; j < 4; ++j) {
        d[j] = fmaf(z[j][c4 * 4 + 0], cc.x, d[j]);
        d[j] = fmaf(z[j][c4 * 4 + 1], cc.y, d[j]);
        d[j] = fmaf(z[j][c4 * 4 + 2], cc.z, d[j]);
        d[j] = fmaf(z[j][c4 * 4 + 3], cc.w, d[j]);
      }
    }
    const float cl = cbnl[k];
    const int kk = chunk * 64 + k;
#pragma unroll
    for (int j = 0; j < 4; ++j) {
      const float dd = cl - 2.f * d[j];
      if (dd < best[j]) { best[j] = dd; bk[j] = kk; }
    }
  }

#pragma unroll
  for (int j = 0; j < 4; ++j) {
    const int pos = pos0 + j * 256;
    bd[chunk * 65536 + pos]  = best[j];
    bki[chunk * 65536 + pos] = bk[j];
  }
}

__global__ __launch_bounds__(BLK) void quantm_k(
    const float* __restrict__ y3, const float* __restrict__ cbg,
    const float* __restrict__ sc, const float* __restrict__ sh,
    const float* __restrict__ bd, const int* __restrict__ bki,
    float* __restrict__ qout, float* __restrict__ idx_out,
    float* __restrict__ pq)
{
  const int pos = blockIdx.x * BLK + threadIdx.x;
  float best = 3.402823466e38f;
  int bk = 0;
#pragma unroll
  for (int s = 0; s < 8; ++s) {
    const float d = bd[s * 65536 + pos];
    const int   k = bki[s * 65536 + pos];
    if (d < best) { best = d; bk = k; }
  }

  const int b = pos >> 10, p = pos & 1023;
  const float4* qrow = (const float4*)(cbg + (size_t)bk * 32);
  float msd = 0.f;
#pragma unroll
  for (int c4 = 0; c4 < 8; ++c4) {
    const float4 q4 = qrow[c4];
    const float qv[4] = {q4.x, q4.y, q4.z, q4.w};
#pragma unroll
    for (int u = 0; u < 4; ++u) {
      const int c = c4 * 4 + u;
      const float v  = y3[((size_t)(b * 32 + c)) * 1024 + p];
      const float zz = fmaxf(fmaf(sc[c], v, sh[c]), 0.f);
      const float qq = qv[u];
      qout[((size_t)(b * 32 + c)) * 1024 + p] = zz + (qq - zz);
      const float df = qq - zz;
      msd = fmaf(df, df, msd);
    }
  }
  idx_out[pos] = (float)bk;
  block_stats2(msd, 0.f, pq + (size_t)blockIdx.x * 2);
}

// ====================== final BN + recon-loss partials ======================

__global__ __launch_bounds__(BLK) void final4_k(
    const float* __restrict__ y6, const float* __restrict__ x,
    const float* __restrict__ sc, const float* __restrict__ sh,
    float* __restrict__ out, float* __restrict__ pr)
{
  const size_t i = ((size_t)blockIdx.x * BLK + threadIdx.x) * 4;
  const float s0 = sc[0], h0 = sh[0];
  const float4 yv = *(const float4*)(y6 + i);
  const float4 xv = *(const float4*)(x + i);
  float4 ov;
  ov.x = fmaf(s0, yv.x, h0);
  ov.y = fmaf(s0, yv.y, h0);
  ov.z = fmaf(s0, yv.z, h0);
  ov.w = fmaf(s0, yv.w, h0);
  *(float4*)(out + i) = ov;
  const float d0 = xv.x - ov.x, d1 = xv.y - ov.y, d2 = xv.z - ov.z, d3 = xv.w - ov.w;
  float s = d0 * d0;
  s = fmaf(d1, d1, s);
  s = fmaf(d2, d2, s);
  s = fmaf(d3, d3, s);
  block_stats2(s, 0.f, pr + (size_t)blockIdx.x * 2);
}

// ============================ loss finalize =================================

__global__ __launch_bounds__(BLK) void loss_k(
    const float* __restrict__ pq, const float* __restrict__ pr,
    float* __restrict__ lossOut)
{
  double s = 0.0, r = 0.0;
  for (int i = threadIdx.x; i < 256; i += BLK)  s += (double)pq[i * 2];
  for (int i = threadIdx.x; i < 4096; i += BLK) r += (double)pr[i * 2];
  __shared__ double lds[8];
  const int lane = threadIdx.x & 63, wv = threadIdx.x >> 6;
#pragma unroll
  for (int off = 32; off > 0; off >>= 1) {
    s += __shfl_down(s, off, 64);
    r += __shfl_down(r, off, 64);
  }
  if (lane == 0) { lds[wv * 2] = s; lds[wv * 2 + 1] = r; }
  __syncthreads();
  if (threadIdx.x == 0) {
    s = lds[0] + lds[2] + lds[4] + lds[6];
    r = lds[1] + lds[3] + lds[5] + lds[7];
    lossOut[0] = (float)(1.2 * (s / 2097152.0) + r / 4194304.0);
  }
}

// ================================ launch ====================================

extern "C" void kernel_launch(void* const* d_in, const int* in_sizes, int n_in,
                              void* d_out, int out_size, void* d_ws, size_t ws_size,
                              hipStream_t stream) {
  const float* x    = (const float*)d_in[0];
  const float* ew1  = (const float*)d_in[1];
  const float* eb1  = (const float*)d_in[2];
  const float* ew2  = (const float*)d_in[3];
  const float* eb2  = (const float*)d_in[4];
  const float* ew3  = (const float*)d_in[5];
  const float* eb3  = (const float*)d_in[6];
  const float* eg1  = (const float*)d_in[7];
  const float* ebe1 = (const float*)d_in[8];
  const float* eg2  = (const float*)d_in[9];
  const float* ebe2 = (const float*)d_in[10];
  const float* eg3  = (const float*)d_in[11];
  const float* ebe3 = (const float*)d_in[12];
  const float* cbk  = (const float*)d_in[13];
  const float* dw1  = (const float*)d_in[14];
  const float* db1  = (const float*)d_in[15];
  const float* dw2  = (const float*)d_in[16];
  const float* db2  = (const float*)d_in[17];
  const float* dw3  = (const float*)d_in[18];
  const float* db3  = (const float*)d_in[19];
  const float* dg1  = (const float*)d_in[20];
  const float* dbe1 = (const float*)d_in[21];
  const float* dg2  = (const float*)d_in[22];
  const float* dbe2 = (const float*)d_in[23];
  const float* dg3  = (const float*)d_in[24];
  const float* dbe3 = (const float*)d_in[25];

  float* ws = (float*)d_ws;
  float* outp = (float*)d_out;

  // small meta region (floats)
  float* SC = ws;            // 6 stages * 32
  float* SH = ws + 192;
  float* P1 = ws + 1024;     // 4096*32 = 131072
  float* P2 = ws + 132096;   // 1024*32 = 32768
  float* P3 = ws + 164864;   // 256*64  = 16384
  float* P4 = ws + 181248;   // 1024*32 = 32768
  float* P5 = ws + 214016;   // 2048*32 = 65536
  float* P6 = ws + 345088;   // 1024*2
  float* Pq = ws + 377856;   // 256*2
  float* Pr = ws + 378368;   // 4096*2
  float* CBN = ws + 411648;  // 512
  // transposed weights [ci][kh][kw][co]
  float* WT1  = ws + 412160;           // 256
  float* WT2  = WT1 + 256;             // 4096
  float* WT3  = WT2 + 4096;            // 8192
  float* WTD1 = WT3 + 8192;            // 8192
  float* WTD2 = WTD1 + 8192;           // 4096

  // big buffers (floats); y5 aliases y1, y4 aliases y2 (dead by then)
  float* y1 = ws + 524288;           // [64,16,128,128] = 16,777,216
  float* y2 = y1 + 16777216;         // [64,16,64,64]   =  4,194,304
  float* y3 = y2 + 4194304;          // [64,32,32,32]   =  2,097,152
  float* qo = y3 + 2097152;          // [64,32,32,32]   =  2,097,152
  float* y6 = qo + 2097152;          // [64,1,256,256]  =  4,194,304
  float* y4 = y2;
  float* y5 = y1;
  float* bd  = y2;                   // 8*65536 floats (quant scratch)
  int*   bki = (int*)(y2 + 524288);  // 8*65536 ints

  float* sc1 = SC + 0,  *sh1 = SH + 0;
  float* sc2 = SC + 32, *sh2 = SH + 32;
  float* sc3 = SC + 64, *sh3 = SH + 64;
  float* sc4 = SC + 96, *sh4 = SH + 96;
  float* sc5 = SC + 128,*sh5 = SH + 128;
  float* sc6 = SC + 160,*sh6 = SH + 160;

  // weight transposes + codebook norms (cheap, run first)
  twc_k<<<1, BLK, 0, stream>>>(ew1, WT1, 1, 16);
  twc_k<<<1, BLK, 0, stream>>>(ew2, WT2, 16, 16);
  twc_k<<<1, BLK, 0, stream>>>(ew3, WT3, 16, 32);
  twt_k<<<1, BLK, 0, stream>>>(dw1, WTD1, 32, 16);
  twt_k<<<1, BLK, 0, stream>>>(dw2, WTD2, 16, 16);
  cbn_k<<<2, BLK, 0, stream>>>(cbk, CBN);

  // ---- encoder (bit-identical chains & partial grouping vs round 7) ----
  conv_cg<1, 16, 2, 4, 256, 256, false><<<4096, 512, 0, stream>>>(x,  WT1, eb1, nullptr, nullptr, y1, P1);
  stats_k<16><<<16, BLK, 0, stream>>>(P1, 4096, 1048576.0, eg1, ebe1, sc1, sh1);
  conv_cg<16, 16, 2, 4, 128, 128, true><<<1024, 512, 0, stream>>>(y1, WT2, eb2, sc1, sh1, y2, P2);
  stats_k<16><<<16, BLK, 0, stream>>>(P2, 1024, 262144.0, eg2, ebe2, sc2, sh2);
  conv_cg<16, 32, 4, 4, 64, 64, true><<<256, 1024, 0, stream>>>(y2, WT3, eb3, sc2, sh2, y3, P3);
  stats_k<32><<<32, BLK, 0, stream>>>(P3, 256, 65536.0, eg3, ebe3, sc3, sh3);

  // ---- quantizer ----
  quantp_k<<<512, BLK, 0, stream>>>(y3, cbk, CBN, sc3, sh3, bd, bki);
  quantm_k<<<256, BLK, 0, stream>>>(y3, cbk, sc3, sh3, bd, bki, qo, outp + 4194305, Pq);

  // ---- decoder: parity-quad convT with wave-cg split ----
  convTq_cg<32, 4, 1, 32, false><<<1024, 256, 0, stream>>>(qo, WTD1, db1, nullptr, nullptr, y4, P4);
  stats_k<16><<<16, BLK, 0, stream>>>(P4, 1024, 262144.0, dg1, dbe1, sc4, sh4);
  convTq_cg<16, 2, 2, 64, true><<<2048, 256, 0, stream>>>(y4, WTD2, db2, sc4, sh4, y5, P5);
  stats_k<16><<<16, BLK, 0, stream>>>(P5, 2048, 1048576.0, dg2, dbe2, sc5, sh5);
  convT3q_k<<<1024, BLK, 0, stream>>>(y5, dw3, db3, sc5, sh5, y6, P6);
  stats_k<1><<<1, BLK, 0, stream>>>(P6, 1024, 4194304.0, dg3, dbe3, sc6, sh6);

  // ---- final BN + losses ----
  final4_k<<<4096, BLK, 0, stream>>>(y6, x, sc6, sh6, outp, Pr);
  loss_k<<<1, BLK, 0, stream>>>(Pq, Pr, outp + 4194304);
}

// Round 9
// 621.788 us; speedup vs baseline: 1.5124x; 1.5124x over previous
//
#include <hip/hip_runtime.h>

#define BLK 256

// ============================== helpers =====================================

__device__ __forceinline__ void block_stats2(float s, float q, float* partOut) {
  __shared__ float red2[2][4];
  const int lane = threadIdx.x & 63;
  const int wv   = threadIdx.x >> 6;
#pragma unroll
  for (int off = 32; off > 0; off >>= 1) {
    s += __shfl_down(s, off, 64);
    q += __shfl_down(q, off, 64);
  }
  if (lane == 0) { red2[0][wv] = s; red2[1][wv] = q; }
  __syncthreads();
  if (threadIdx.x == 0) {
    partOut[0] = red2[0][0] + red2[0][1] + red2[0][2] + red2[0][3];
    partOut[1] = red2[1][0] + red2[1][1] + red2[1][2] + red2[1][3];
  }
}

// ======================= weight transpose kernels ===========================
// target layout wt[((ci*4+kh)*4+kw)*CO + co]  (co contiguous -> s_load)

__global__ __launch_bounds__(BLK) void twc_k(const float* __restrict__ w,
                                             float* __restrict__ wt,
                                             int CI, int CO) {
  const int total = CI * CO * 16;
  for (int i = threadIdx.x; i < total; i += BLK) {
    const int co = i % CO;
    const int rest = i / CO;
    const int kw = rest & 3, kh = (rest >> 2) & 3, ci = rest >> 4;
    wt[i] = w[(co * CI + ci) * 16 + kh * 4 + kw];     // conv: w[co][ci][kh][kw]
  }
}

__global__ __launch_bounds__(BLK) void twt_k(const float* __restrict__ w,
                                             float* __restrict__ wt,
                                             int CI, int CO) {
  const int total = CI * CO * 16;
  for (int i = threadIdx.x; i < total; i += BLK) {
    const int co = i % CO;
    const int rest = i / CO;
    const int kw = rest & 3, kh = (rest >> 2) & 3, ci = rest >> 4;
    wt[i] = w[(ci * CO + co) * 16 + kh * 4 + kw];     // convT: w[ci][co][kh][kw]
  }
}

// ============ conv (k4 s2 p1), wave-cg split, scalar-mem weights ============
// co0 forced into SGPR via readfirstlane -> weight reads become s_load.
// FMA chain per co IDENTICAL to round-6/7/8 (kh->kw->ci, same skips); BN
// partials same grouping -> encoder bit-identical.

template<int CI, int CO, int CGN, int PW, int HIN, int WIN, bool BN_IN>
__global__ __launch_bounds__(64 * PW * CGN) void conv_cg(
    const float* __restrict__ in, const float* __restrict__ wt,
    const float* __restrict__ bias,
    const float* __restrict__ scIn, const float* __restrict__ shIn,
    float* __restrict__ out, float* __restrict__ part)
{
  constexpr int HOUT = HIN / 2, WOUT = WIN / 2;
  constexpr int COG = CO / CGN;
  const int lane = threadIdx.x & 63;
  const int w    = threadIdx.x >> 6;
  const int pw   = w & (PW - 1);
  const int cg   = w / PW;
  // wave-uniform by construction; readfirstlane makes it PROVABLY uniform
  const int co0  = __builtin_amdgcn_readfirstlane(cg * COG);

  float sc[CI], sh[CI];
  if constexpr (BN_IN) {
#pragma unroll
    for (int ci = 0; ci < CI; ++ci) { sc[ci] = scIn[ci]; sh[ci] = shIn[ci]; }
  }

  const int pos = blockIdx.x * (64 * PW) + pw * 64 + lane;
  const int ow  = pos % WOUT;
  const int oh  = (pos / WOUT) % HOUT;
  const int b   = pos / (WOUT * HOUT);

  float acc[COG];
#pragma unroll
  for (int j = 0; j < COG; ++j) acc[j] = bias[co0 + j];

  const float* inb = in + (size_t)b * CI * HIN * WIN;

#pragma unroll
  for (int kh = 0; kh < 4; ++kh) {
    const int ih = oh * 2 - 1 + kh;
    if ((unsigned)ih < (unsigned)HIN) {
#pragma unroll
      for (int kw = 0; kw < 4; ++kw) {
        const int iw = ow * 2 - 1 + kw;
        if ((unsigned)iw < (unsigned)WIN) {
#pragma unroll 2
          for (int ci = 0; ci < CI; ++ci) {
            float v = inb[(ci * HIN + ih) * WIN + iw];
            if constexpr (BN_IN) v = fmaxf(fmaf(sc[ci], v, sh[ci]), 0.f);
            const float* wrow = wt + ((ci * 4 + kh) * 4 + kw) * CO + co0; // SGPR
#pragma unroll
            for (int j = 0; j < COG; ++j)
              acc[j] = fmaf(v, wrow[j], acc[j]);
          }
        }
      }
    }
  }

#pragma unroll
  for (int j = 0; j < COG; ++j)
    out[((size_t)(b * CO + co0 + j) * HOUT + oh) * WOUT + ow] = acc[j];

  // BN partials: per-wave 64-lane tree, then sum PW pos-waves in order.
  float s[COG], q[COG];
#pragma unroll
  for (int j = 0; j < COG; ++j) { s[j] = acc[j]; q[j] = acc[j] * acc[j]; }
#pragma unroll
  for (int off = 32; off > 0; off >>= 1)
#pragma unroll
    for (int j = 0; j < COG; ++j) {
      s[j] += __shfl_down(s[j], off, 64);
      q[j] += __shfl_down(q[j], off, 64);
    }
  __shared__ float red[CGN * PW][COG][2];
  if (lane == 0) {
#pragma unroll
    for (int j = 0; j < COG; ++j) { red[w][j][0] = s[j]; red[w][j][1] = q[j]; }
  }
  __syncthreads();
  if (threadIdx.x < CO) {
    const int co = threadIdx.x;
    const int cg2 = co / COG, j = co % COG;
    float ss = 0.f, qq = 0.f;
#pragma unroll
    for (int p2 = 0; p2 < PW; ++p2) {
      ss += red[cg2 * PW + p2][j][0];
      qq += red[cg2 * PW + p2][j][1];
    }
    part[(size_t)blockIdx.x * CO * 2 + co * 2]     = ss;
    part[(size_t)blockIdx.x * CO * 2 + co * 2 + 1] = qq;
  }
}

// ===== transposed conv parity-quad, wave-cg split (CO=16, s_load weights) ===

template<int CI, int CGN, int PW, int HIN, bool BN_IN>
__global__ __launch_bounds__(64 * PW * CGN) void convTq_cg(
    const float* __restrict__ in, const float* __restrict__ wt,
    const float* __restrict__ bias,
    const float* __restrict__ scIn, const float* __restrict__ shIn,
    float* __restrict__ out, float* __restrict__ part)
{
  constexpr int WIN = HIN, HOUT = 2 * HIN, WOUT = 2 * WIN;
  constexpr int COG = 16 / CGN;
  const int lane = threadIdx.x & 63;
  const int w    = threadIdx.x >> 6;
  const int pw   = w & (PW - 1);
  const int cg   = w / PW;
  const int co0  = __builtin_amdgcn_readfirstlane(cg * COG);  // SGPR

  const int q_  = blockIdx.x * (64 * PW) + pw * 64 + lane;
  const int qw  = q_ % WIN;
  const int qh  = (q_ / WIN) % HIN;
  const int b   = q_ / (WIN * HIN);

  constexpr int KH[2][2] = {{1, 3}, {0, 2}};
  constexpr int PR[2][2] = {{1, 0}, {2, 1}};

  float acc[2][2][COG];
#pragma unroll
  for (int j = 0; j < COG; ++j) {
    const float bv = bias[co0 + j];
    acc[0][0][j] = bv; acc[0][1][j] = bv;
    acc[1][0][j] = bv; acc[1][1][j] = bv;
  }

  const float* inb = in + (size_t)b * CI * HIN * WIN;

#pragma unroll 2
  for (int ci = 0; ci < CI; ++ci) {
    float sci, shi;
    if constexpr (BN_IN) { sci = scIn[ci]; shi = shIn[ci]; }
    const float* base = inb + ci * HIN * WIN;
    float v[3][3];
#pragma unroll
    for (int pr = 0; pr < 3; ++pr) {
      const int ih = qh - 1 + pr;
      const bool okr = (unsigned)ih < (unsigned)HIN;
#pragma unroll
      for (int pc = 0; pc < 3; ++pc) {
        const int iw = qw - 1 + pc;
        float val = 0.f;
        if (okr && (unsigned)iw < (unsigned)WIN) {
          val = base[ih * WIN + iw];
          if constexpr (BN_IN) val = fmaxf(fmaf(sci, val, shi), 0.f);
        }
        v[pr][pc] = val;
      }
    }
#pragma unroll
    for (int py = 0; py < 2; ++py)
#pragma unroll
      for (int tr = 0; tr < 2; ++tr) {
        const int kh = KH[py][tr], pr_ = PR[py][tr];
#pragma unroll
        for (int px = 0; px < 2; ++px)
#pragma unroll
          for (int tc = 0; tc < 2; ++tc) {
            const int kw = KH[px][tc], pc_ = PR[px][tc];
            const float* wrow = wt + ((ci * 4 + kh) * 4 + kw) * 16 + co0; // SGPR
            const float pv = v[pr_][pc_];
#pragma unroll
            for (int j = 0; j < COG; ++j)
              acc[py][px][j] = fmaf(pv, wrow[j], acc[py][px][j]);
          }
      }
  }

  float* ob = out + (size_t)b * 16 * HOUT * WOUT;
#pragma unroll
  for (int j = 0; j < COG; ++j)
#pragma unroll
    for (int py = 0; py < 2; ++py) {
      float2 o; o.x = acc[py][0][j]; o.y = acc[py][1][j];
      *(float2*)&ob[((size_t)(co0 + j) * HOUT + 2 * qh + py) * WOUT + 2 * qw] = o;
    }

  float s[COG], q[COG];
#pragma unroll
  for (int j = 0; j < COG; ++j) {
    float a = acc[0][0][j] + acc[0][1][j] + acc[1][0][j] + acc[1][1][j];
    float qq = acc[0][0][j] * acc[0][0][j];
    qq = fmaf(acc[0][1][j], acc[0][1][j], qq);
    qq = fmaf(acc[1][0][j], acc[1][0][j], qq);
    qq = fmaf(acc[1][1][j], acc[1][1][j], qq);
    s[j] = a; q[j] = qq;
  }
#pragma unroll
  for (int off = 32; off > 0; off >>= 1)
#pragma unroll
    for (int j = 0; j < COG; ++j) {
      s[j] += __shfl_down(s[j], off, 64);
      q[j] += __shfl_down(q[j], off, 64);
    }
  __shared__ float red[CGN * PW][COG][2];
  if (lane == 0) {
#pragma unroll
    for (int j = 0; j < COG; ++j) { red[w][j][0] = s[j]; red[w][j][1] = q[j]; }
  }
  __syncthreads();
  if (threadIdx.x < 16) {
    const int co = threadIdx.x;
    const int cg2 = co / COG, j = co % COG;
    float ss = 0.f, qq = 0.f;
#pragma unroll
    for (int p2 = 0; p2 < PW; ++p2) {
      ss += red[cg2 * PW + p2][j][0];
      qq += red[cg2 * PW + p2][j][1];
    }
    part[(size_t)blockIdx.x * 32 + co * 2]     = ss;
    part[(size_t)blockIdx.x * 32 + co * 2 + 1] = qq;
  }
}

// ==================== convT3: 4x4-tile version (CI=16, CO=1) ================
// (unchanged — verified)

__global__ __launch_bounds__(BLK) void convT3q_k(
    const float* __restrict__ in, const float* __restrict__ w,
    const float* __restrict__ bias,
    const float* __restrict__ scIn, const float* __restrict__ shIn,
    float* __restrict__ out, float* __restrict__ part)
{
  __shared__ float wl[256];               // [ci][kh][kw]
  wl[threadIdx.x] = w[threadIdx.x];
  float sc[16], sh[16];
#pragma unroll
  for (int ci = 0; ci < 16; ++ci) { sc[ci] = scIn[ci]; sh[ci] = shIn[ci]; }
  const float b0 = bias[0];
  __syncthreads();

  const int idx = blockIdx.x * BLK + threadIdx.x;
  const int tx = idx & 63;
  const int ty = (idx >> 6) & 63;
  const int b  = idx >> 12;
  const int i0 = ty * 2, j0 = tx * 2;

  constexpr int TAP[4][4] = {{1,1,3,0},{0,2,2,1},{1,2,3,1},{0,3,2,2}};

  float acc[4][4];
#pragma unroll
  for (int r = 0; r < 4; ++r)
#pragma unroll
    for (int c = 0; c < 4; ++c) acc[r][c] = b0;

  const float* inb = in + (size_t)b * 16 * 16384;

#pragma unroll 4
  for (int ci = 0; ci < 16; ++ci) {
    const float sci = sc[ci], shi = sh[ci];
    const float* base = inb + ci * 16384;
    float v[4][4];
#pragma unroll
    for (int pr = 0; pr < 4; ++pr) {
      const int ih = i0 - 1 + pr;
      const bool okr = (unsigned)ih < 128u;
#pragma unroll
      for (int pc = 0; pc < 4; ++pc) {
        const int iw = j0 - 1 + pc;
        float val = 0.f;
        if (okr && (unsigned)iw < 128u)
          val = fmaxf(fmaf(sci, base[ih * 128 + iw], shi), 0.f);
        v[pr][pc] = val;
      }
    }
    const float4 w0 = *(const float4*)&wl[ci * 16 + 0];
    const float4 w1 = *(const float4*)&wl[ci * 16 + 4];
    const float4 w2 = *(const float4*)&wl[ci * 16 + 8];
    const float4 w3 = *(const float4*)&wl[ci * 16 + 12];
    const float wg[16] = {w0.x,w0.y,w0.z,w0.w, w1.x,w1.y,w1.z,w1.w,
                          w2.x,w2.y,w2.z,w2.w, w3.x,w3.y,w3.z,w3.w};
#pragma unroll
    for (int r = 0; r < 4; ++r) {
      const int k1r = TAP[r][0], p1r = TAP[r][1], k2r = TAP[r][2], p2r = TAP[r][3];
#pragma unroll
      for (int c = 0; c < 4; ++c) {
        const int k1c = TAP[c][0], p1c = TAP[c][1], k2c = TAP[c][2], p2c = TAP[c][3];
        float a = acc[r][c];
        a = fmaf(v[p1r][p1c], wg[k1r * 4 + k1c], a);
        a = fmaf(v[p1r][p2c], wg[k1r * 4 + k2c], a);
        a = fmaf(v[p2r][p1c], wg[k2r * 4 + k1c], a);
        a = fmaf(v[p2r][p2c], wg[k2r * 4 + k2c], a);
        acc[r][c] = a;
      }
    }
  }

  float* ob = out + (size_t)b * 65536;
#pragma unroll
  for (int r = 0; r < 4; ++r) {
    float4 o;
    o.x = acc[r][0]; o.y = acc[r][1]; o.z = acc[r][2]; o.w = acc[r][3];
    *(float4*)&ob[(ty * 4 + r) * 256 + tx * 4] = o;
  }

  float s = 0.f, q = 0.f;
#pragma unroll
  for (int r = 0; r < 4; ++r)
#pragma unroll
    for (int c = 0; c < 4; ++c) { s += acc[r][c]; q = fmaf(acc[r][c], acc[r][c], q); }
  block_stats2(s, q, part + (size_t)blockIdx.x * 2);
}

// =========================== BN stats reduction =============================

template<int C>
__global__ __launch_bounds__(BLK) void stats_k(
    const float* __restrict__ part, int nB, double N,
    const float* __restrict__ g, const float* __restrict__ be,
    float* __restrict__ sc, float* __restrict__ sh)
{
  const int c = blockIdx.x;
  double s0 = 0.0, s1 = 0.0;
  for (int i = threadIdx.x; i < nB; i += BLK) {
    s0 += (double)part[(size_t)i * C * 2 + c * 2];
    s1 += (double)part[(size_t)i * C * 2 + c * 2 + 1];
  }
  __shared__ double lds[8];
  const int lane = threadIdx.x & 63, wv = threadIdx.x >> 6;
#pragma unroll
  for (int off = 32; off > 0; off >>= 1) {
    s0 += __shfl_down(s0, off, 64);
    s1 += __shfl_down(s1, off, 64);
  }
  if (lane == 0) { lds[wv * 2] = s0; lds[wv * 2 + 1] = s1; }
  __syncthreads();
  if (threadIdx.x == 0) {
    s0 = lds[0] + lds[2] + lds[4] + lds[6];
    s1 = lds[1] + lds[3] + lds[5] + lds[7];
    const double mean = s0 / N;
    const double var  = s1 / N - mean * mean;
    const double inv  = 1.0 / sqrt(var + 1e-5);
    sc[c] = (float)((double)g[c] * inv);
    sh[c] = (float)((double)be[c] - mean * (double)g[c] * inv);
  }
}

// ============================== quantizer ===================================

__global__ __launch_bounds__(BLK) void cbn_k(const float* __restrict__ cbg,
                                             float* __restrict__ cbn)
{
  const int k = blockIdx.x * BLK + threadIdx.x;
  float s = 0.f;
#pragma unroll
  for (int c = 0; c < 32; ++c) {
    const float x = cbg[k * 32 + c];
    s = fmaf(x, x, s);
  }
  cbn[k] = s;
}

__global__ __launch_bounds__(BLK) void quantp_k(
    const float* __restrict__ y3, const float* __restrict__ cbg,
    const float* __restrict__ cbnG,
    const float* __restrict__ sc, const float* __restrict__ sh,
    float* __restrict__ bd, int* __restrict__ bki)
{
  __shared__ float cb[64 * 32];
  __shared__ float cbnl[64];
  const int pblk  = blockIdx.x & 63;
  const int chunk = blockIdx.x >> 6;
  for (int i = threadIdx.x; i < 2048; i += BLK) cb[i] = cbg[chunk * 2048 + i];
  if (threadIdx.x < 64) cbnl[threadIdx.x] = cbnG[chunk * 64 + threadIdx.x];
  __syncthreads();

  const int pos0 = pblk * 1024 + threadIdx.x;

  float z[4][32];
#pragma unroll
  for (int c = 0; c < 32; ++c) {
    const float s_ = sc[c], h_ = sh[c];
#pragma unroll
    for (int j = 0; j < 4; ++j) {
      const int pos = pos0 + j * 256;
      const int bb = pos >> 10, pp = pos & 1023;
      z[j][c] = fmaxf(fmaf(s_, y3[((size_t)(bb * 32 + c)) * 1024 + pp], h_), 0.f);
    }
  }

  float best[4] = {3.402823466e38f, 3.402823466e38f, 3.402823466e38f, 3.402823466e38f};
  int   bk[4]   = {0, 0, 0, 0};

  for (int k = 0; k < 64; ++k) {
    const float4* row = (const float4*)&cb[k * 32];
    float d[4] = {0.f, 0.f, 0.f, 0.f};
#pragma unroll
    for (int c4 = 0; c4 < 8; ++c4) {
      const float4 cc = row[c4];
#pragma unroll
      for (int j = 0; j < 4; ++j) {
        d[j] = fmaf(z[j][c4 * 4 + 0], cc.x, d[j]);
        d[j] = fmaf(z[j][c4 * 4 + 1], cc.y, d[j]);
        d[j] = fmaf(z[j][c4 * 4 + 2], cc.z, d[j]);
        d[j] = fmaf(z[j][c4 * 4 + 3], cc.w, d[j]);
      }
    }
    const float cl = cbnl[k];
    const int kk = chunk * 64 + k;
#pragma unroll
    for (int j = 0; j < 4; ++j) {
      const float dd = cl - 2.f * d[j];
      if (dd < best[j]) { best[j] = dd; bk[j] = kk; }
    }
  }

#pragma unroll
  for (int j = 0; j < 4; ++j) {
    const int pos = pos0 + j * 256;
    bd[chunk * 65536 + pos]  = best[j];
    bki[chunk * 65536 + pos] = bk[j];
  }
}

__global__ __launch_bounds__(BLK) void quantm_k(
    const float* __restrict__ y3, const float* __restrict__ cbg,
    const float* __restrict__ sc, const float* __restrict__ sh,
    const float* __restrict__ bd, const int* __restrict__ bki,
    float* __restrict__ qout, float* __restrict__ idx_out,
    float* __restrict__ pq)
{
  const int pos = blockIdx.x * BLK + threadIdx.x;
  float best = 3.402823466e38f;
  int bk = 0;
#pragma unroll
  for (int s = 0; s < 8; ++s) {
    const float d = bd[s * 65536 + pos];
    const int   k = bki[s * 65536 + pos];
    if (d < best) { best = d; bk = k; }
  }

  const int b = pos >> 10, p = pos & 1023;
  const float4* qrow = (const float4*)(cbg + (size_t)bk * 32);
  float msd = 0.f;
#pragma unroll
  for (int c4 = 0; c4 < 8; ++c4) {
    const float4 q4 = qrow[c4];
    const float qv[4] = {q4.x, q4.y, q4.z, q4.w};
#pragma unroll
    for (int u = 0; u < 4; ++u) {
      const int c = c4 * 4 + u;
      const float v  = y3[((size_t)(b * 32 + c)) * 1024 + p];
      const float zz = fmaxf(fmaf(sc[c], v, sh[c]), 0.f);
      const float qq = qv[u];
      qout[((size_t)(b * 32 + c)) * 1024 + p] = zz + (qq - zz);
      const float df = qq - zz;
      msd = fmaf(df, df, msd);
    }
  }
  idx_out[pos] = (float)bk;
  block_stats2(msd, 0.f, pq + (size_t)blockIdx.x * 2);
}

// ====================== final BN + recon-loss partials ======================

__global__ __launch_bounds__(BLK) void final4_k(
    const float* __restrict__ y6, const float* __restrict__ x,
    const float* __restrict__ sc, const float* __restrict__ sh,
    float* __restrict__ out, float* __restrict__ pr)
{
  const size_t i = ((size_t)blockIdx.x * BLK + threadIdx.x) * 4;
  const float s0 = sc[0], h0 = sh[0];
  const float4 yv = *(const float4*)(y6 + i);
  const float4 xv = *(const float4*)(x + i);
  float4 ov;
  ov.x = fmaf(s0, yv.x, h0);
  ov.y = fmaf(s0, yv.y, h0);
  ov.z = fmaf(s0, yv.z, h0);
  ov.w = fmaf(s0, yv.w, h0);
  *(float4*)(out + i) = ov;
  const float d0 = xv.x - ov.x, d1 = xv.y - ov.y, d2 = xv.z - ov.z, d3 = xv.w - ov.w;
  float s = d0 * d0;
  s = fmaf(d1, d1, s);
  s = fmaf(d2, d2, s);
  s = fmaf(d3, d3, s);
  block_stats2(s, 0.f, pr + (size_t)blockIdx.x * 2);
}

// ============================ loss finalize =================================

__global__ __launch_bounds__(BLK) void loss_k(
    const float* __restrict__ pq, const float* __restrict__ pr,
    float* __restrict__ lossOut)
{
  double s = 0.0, r = 0.0;
  for (int i = threadIdx.x; i < 256; i += BLK)  s += (double)pq[i * 2];
  for (int i = threadIdx.x; i < 4096; i += BLK) r += (double)pr[i * 2];
  __shared__ double lds[8];
  const int lane = threadIdx.x & 63, wv = threadIdx.x >> 6;
#pragma unroll
  for (int off = 32; off > 0; off >>= 1) {
    s += __shfl_down(s, off, 64);
    r += __shfl_down(r, off, 64);
  }
  if (lane == 0) { lds[wv * 2] = s; lds[wv * 2 + 1] = r; }
  __syncthreads();
  if (threadIdx.x == 0) {
    s = lds[0] + lds[2] + lds[4] + lds[6];
    r = lds[1] + lds[3] + lds[5] + lds[7];
    lossOut[0] = (float)(1.2 * (s / 2097152.0) + r / 4194304.0);
  }
}

// ================================ launch ====================================

extern "C" void kernel_launch(void* const* d_in, const int* in_sizes, int n_in,
                              void* d_out, int out_size, void* d_ws, size_t ws_size,
                              hipStream_t stream) {
  const float* x    = (const float*)d_in[0];
  const float* ew1  = (const float*)d_in[1];
  const float* eb1  = (const float*)d_in[2];
  const float* ew2  = (const float*)d_in[3];
  const float* eb2  = (const float*)d_in[4];
  const float* ew3  = (const float*)d_in[5];
  const float* eb3  = (const float*)d_in[6];
  const float* eg1  = (const float*)d_in[7];
  const float* ebe1 = (const float*)d_in[8];
  const float* eg2  = (const float*)d_in[9];
  const float* ebe2 = (const float*)d_in[10];
  const float* eg3  = (const float*)d_in[11];
  const float* ebe3 = (const float*)d_in[12];
  const float* cbk  = (const float*)d_in[13];
  const float* dw1  = (const float*)d_in[14];
  const float* db1  = (const float*)d_in[15];
  const float* dw2  = (const float*)d_in[16];
  const float* db2  = (const float*)d_in[17];
  const float* dw3  = (const float*)d_in[18];
  const float* db3  = (const float*)d_in[19];
  const float* dg1  = (const float*)d_in[20];
  const float* dbe1 = (const float*)d_in[21];
  const float* dg2  = (const float*)d_in[22];
  const float* dbe2 = (const float*)d_in[23];
  const float* dg3  = (const float*)d_in[24];
  const float* dbe3 = (const float*)d_in[25];

  float* ws = (float*)d_ws;
  float* outp = (float*)d_out;

  // small meta region (floats)
  float* SC = ws;            // 6 stages * 32
  float* SH = ws + 192;
  float* P1 = ws + 1024;     // 4096*32 = 131072
  float* P2 = ws + 132096;   // 1024*32 = 32768
  float* P3 = ws + 164864;   // 256*64  = 16384
  float* P4 = ws + 181248;   // 1024*32 = 32768
  float* P5 = ws + 214016;   // 2048*32 = 65536
  float* P6 = ws + 345088;   // 1024*2
  float* Pq = ws + 377856;   // 256*2
  float* Pr = ws + 378368;   // 4096*2
  float* CBN = ws + 411648;  // 512
  // transposed weights [ci][kh][kw][co]
  float* WT1  = ws + 412160;           // 256
  float* WT2  = WT1 + 256;             // 4096
  float* WT3  = WT2 + 4096;            // 8192
  float* WTD1 = WT3 + 8192;            // 8192
  float* WTD2 = WTD1 + 8192;           // 4096

  // big buffers (floats); y5 aliases y1, y4 aliases y2 (dead by then)
  float* y1 = ws + 524288;           // [64,16,128,128] = 16,777,216
  float* y2 = y1 + 16777216;         // [64,16,64,64]   =  4,194,304
  float* y3 = y2 + 4194304;          // [64,32,32,32]   =  2,097,152
  float* qo = y3 + 2097152;          // [64,32,32,32]   =  2,097,152
  float* y6 = qo + 2097152;          // [64,1,256,256]  =  4,194,304
  float* y4 = y2;
  float* y5 = y1;
  float* bd  = y2;                   // 8*65536 floats (quant scratch)
  int*   bki = (int*)(y2 + 524288);  // 8*65536 ints

  float* sc1 = SC + 0,  *sh1 = SH + 0;
  float* sc2 = SC + 32, *sh2 = SH + 32;
  float* sc3 = SC + 64, *sh3 = SH + 64;
  float* sc4 = SC + 96, *sh4 = SH + 96;
  float* sc5 = SC + 128,*sh5 = SH + 128;
  float* sc6 = SC + 160,*sh6 = SH + 160;

  // weight transposes + codebook norms (cheap, run first)
  twc_k<<<1, BLK, 0, stream>>>(ew1, WT1, 1, 16);
  twc_k<<<1, BLK, 0, stream>>>(ew2, WT2, 16, 16);
  twc_k<<<1, BLK, 0, stream>>>(ew3, WT3, 16, 32);
  twt_k<<<1, BLK, 0, stream>>>(dw1, WTD1, 32, 16);
  twt_k<<<1, BLK, 0, stream>>>(dw2, WTD2, 16, 16);
  cbn_k<<<2, BLK, 0, stream>>>(cbk, CBN);

  // ---- encoder (bit-identical chains & partial grouping) ----
  conv_cg<1, 16, 2, 4, 256, 256, false><<<4096, 512, 0, stream>>>(x,  WT1, eb1, nullptr, nullptr, y1, P1);
  stats_k<16><<<16, BLK, 0, stream>>>(P1, 4096, 1048576.0, eg1, ebe1, sc1, sh1);
  conv_cg<16, 16, 2, 4, 128, 128, true><<<1024, 512, 0, stream>>>(y1, WT2, eb2, sc1, sh1, y2, P2);
  stats_k<16><<<16, BLK, 0, stream>>>(P2, 1024, 262144.0, eg2, ebe2, sc2, sh2);
  conv_cg<16, 32, 4, 4, 64, 64, true><<<256, 1024, 0, stream>>>(y2, WT3, eb3, sc2, sh2, y3, P3);
  stats_k<32><<<32, BLK, 0, stream>>>(P3, 256, 65536.0, eg3, ebe3, sc3, sh3);

  // ---- quantizer ----
  quantp_k<<<512, BLK, 0, stream>>>(y3, cbk, CBN, sc3, sh3, bd, bki);
  quantm_k<<<256, BLK, 0, stream>>>(y3, cbk, sc3, sh3, bd, bki, qo, outp + 4194305, Pq);

  // ---- decoder: parity-quad convT with wave-cg split ----
  convTq_cg<32, 4, 1, 32, false><<<1024, 256, 0, stream>>>(qo, WTD1, db1, nullptr, nullptr, y4, P4);
  stats_k<16><<<16, BLK, 0, stream>>>(P4, 1024, 262144.0, dg1, dbe1, sc4, sh4);
  convTq_cg<16, 2, 2, 64, true><<<2048, 256, 0, stream>>>(y4, WTD2, db2, sc4, sh4, y5, P5);
  stats_k<16><<<16, BLK, 0, stream>>>(P5, 2048, 1048576.0, dg2, dbe2, sc5, sh5);
  convT3q_k<<<1024, BLK, 0, stream>>>(y5, dw3, db3, sc5, sh5, y6, P6);
  stats_k<1><<<1, BLK, 0, stream>>>(P6, 1024, 4194304.0, dg3, dbe3, sc6, sh6);

  // ---- final BN + losses ----
  final4_k<<<4096, BLK, 0, stream>>>(y6, x, sc6, sh6, outp, Pr);
  loss_k<<<1, BLK, 0, stream>>>(Pq, Pr, outp + 4194304);
}